// Round 6
// baseline (558.291 us; speedup 1.0000x reference)
//
#include <hip/hip_runtime.h>
#include <hip/hip_bf16.h>
#include <math.h>

#define D 128
#define G_GRAPHS 512
#define C_CLASSES 10
#define BN_EPS 1e-5f
#define NBUCK_MAX 512     // supports N <= 131072 (bucket = node >> 8)
#define EDGE_CHUNK 4096
#define EPT 16            // EDGE_CHUNK / 256
#define HIST_BLOCKS 512
#define BN_BLOCKS 512

typedef unsigned short u16;
typedef unsigned int u32;
typedef unsigned short ushort4_t __attribute__((ext_vector_type(4)));
typedef unsigned short ushort8_t __attribute__((ext_vector_type(8)));
typedef __bf16 bf16x8 __attribute__((ext_vector_type(8)));
typedef float floatx4 __attribute__((ext_vector_type(4)));
union B8 { ushort8_t u; bf16x8 b; };

__device__ __forceinline__ float bf_lo(u32 v) { return __uint_as_float(v << 16); }
__device__ __forceinline__ float bf_hi(u32 v) { return __uint_as_float(v & 0xffff0000u); }
__device__ __forceinline__ u16 f2bf(float f) {
    union { float f; u32 u; } x; x.f = f;
    u32 r = x.u + 0x7fff + ((x.u >> 16) & 1);  // RN-even
    return (u16)(r >> 16);
}
__device__ __forceinline__ u32 pack2bf(float a, float b) {
    return (u32)f2bf(a) | ((u32)f2bf(b) << 16);
}

// ============ CSR build: two-level counting sort ============
// blocks >= HIST_BLOCKS run the graph-bounds body (launch fusion)

__global__ __launch_bounds__(256) void bucket_hist_kernel(
    const int* __restrict__ dst, int* __restrict__ bucketCnt, int E, int nbuck,
    const int* __restrict__ batch, int* __restrict__ gstart, int N)
{
    int tid = threadIdx.x;
    if (blockIdx.x >= HIST_BLOCKS) {
        // ---- graph segments: boundary detection on sorted batch ----
        int i = (blockIdx.x - HIST_BLOCKS) * 256 + tid;
        if (i >= N) return;
        int b = batch[i];
        int prev = (i == 0) ? -1 : batch[i - 1];
        if (b != prev) {
            for (int g = prev + 1; g <= b; ++g) gstart[g] = i;  // covers empty graphs
        }
        if (i == N - 1) {
            for (int g = b + 1; g <= G_GRAPHS; ++g) gstart[g] = N;
        }
        return;
    }
    __shared__ int h[NBUCK_MAX];
    for (int i = tid; i < NBUCK_MAX; i += 256) h[i] = 0;
    __syncthreads();
    for (int i = blockIdx.x * 256 + tid; i < E; i += HIST_BLOCKS * 256)
        atomicAdd(&h[dst[i] >> 8], 1);
    __syncthreads();
    for (int i = tid; i < nbuck; i += 256)
        if (h[i]) atomicAdd(&bucketCnt[i], h[i]);
}

__global__ void scan_buckets_kernel(
    const int* __restrict__ bucketCnt, int* __restrict__ bucketBase,
    int* __restrict__ bucketCursor, int* __restrict__ rowPtr, int nbuck, int N, int E)
{
    __shared__ int buf[2][512];
    int tid = threadIdx.x;
    int v = (tid < nbuck) ? bucketCnt[tid] : 0;
    buf[0][tid] = v;
    __syncthreads();
    int cur = 0;
    for (int off = 1; off < 512; off <<= 1) {
        buf[1 - cur][tid] = buf[cur][tid] + ((tid >= off) ? buf[cur][tid - off] : 0);
        cur ^= 1;
        __syncthreads();
    }
    if (tid < nbuck) {
        int b = buf[cur][tid] - v;  // exclusive
        bucketBase[tid] = b;
        bucketCursor[tid] = b;
    }
    if (tid == 0) { bucketBase[nbuck] = E; rowPtr[N] = E; }
}

// pairs packed: (src << 8) | (dst & 255)   [src < 2^17, fits 25 bits]
__global__ __launch_bounds__(256) void scatter_pairs_kernel(
    const int* __restrict__ src, const int* __restrict__ dst,
    int* __restrict__ bucketCursor, u32* __restrict__ pairs, int E)
{
    __shared__ int h[NBUCK_MAX];
    __shared__ int base[NBUCK_MAX];
    int tid = threadIdx.x;
    int e0 = blockIdx.x * EDGE_CHUNK;
    for (int i = tid; i < NBUCK_MAX; i += 256) h[i] = 0;
    __syncthreads();
    int s[EPT], d[EPT], r[EPT];
#pragma unroll
    for (int j = 0; j < EPT; ++j) {
        int i = e0 + j * 256 + tid;
        if (i < E) {
            s[j] = src[i];
            d[j] = dst[i];
            r[j] = atomicAdd(&h[d[j] >> 8], 1);
        } else {
            d[j] = -1;
        }
    }
    __syncthreads();
    for (int i = tid; i < NBUCK_MAX; i += 256)
        if (h[i]) base[i] = atomicAdd(&bucketCursor[i], h[i]);
    __syncthreads();
#pragma unroll
    for (int j = 0; j < EPT; ++j) {
        if (d[j] >= 0) {
            int b = d[j] >> 8;
            pairs[base[b] + r[j]] = ((u32)s[j] << 8) | (u32)(d[j] & 255);
        }
    }
}

// degHist/degCursor: 16 bins, each padded to its own 64B line (stride 16 ints)
__global__ __launch_bounds__(256) void bucket_sort_kernel(
    const u32* __restrict__ pairs, const int* __restrict__ bucketBase,
    int* __restrict__ colIdx, int* __restrict__ rowPtr, float* __restrict__ dinv,
    int* __restrict__ degHist, int N)
{
    __shared__ int h[256];
    __shared__ int cur[256];
    __shared__ int sbuf[2][256];
    __shared__ int dh[16];
    int tid = threadIdx.x;
    int b = blockIdx.x;
    int s = bucketBase[b], e = bucketBase[b + 1];
    h[tid] = 0;
    if (tid < 16) dh[tid] = 0;
    __syncthreads();
    for (int i = s + tid; i < e; i += 256)
        atomicAdd(&h[pairs[i] & 255], 1);
    __syncthreads();
    int cnt = h[tid];
    sbuf[0][tid] = cnt;
    __syncthreads();
    int c = 0;
    for (int off = 1; off < 256; off <<= 1) {
        sbuf[1 - c][tid] = sbuf[c][tid] + ((tid >= off) ? sbuf[c][tid - off] : 0);
        c ^= 1;
        __syncthreads();
    }
    int excl = sbuf[c][tid] - cnt;
    int v = b * 256 + tid;
    if (v < N) {
        rowPtr[v] = s + excl;
        dinv[v] = rsqrtf((float)(cnt + 1));  // +1 self loop
        int key = (cnt + 15) >> 4;           // cost bin = pair count
        if (key > 15) key = 15;
        atomicAdd(&dh[key], 1);              // LDS-local (round-4 lesson: 100k
                                             // same-line global atomics = 788us)
    }
    cur[tid] = s + excl;
    __syncthreads();
    if (tid < 16 && dh[tid]) atomicAdd(&degHist[tid * 16], dh[tid]);  // 16 flushes/block
    for (int i = s + tid; i < e; i += 256) {
        u32 p = pairs[i];
        int pos = atomicAdd(&cur[p & 255], 1);
        colIdx[pos] = (int)(p >> 8);
    }
}

// ---- W pre-transpose+convert; block 3 zeroes T row N; block 4 scans deg bins ----
__global__ __launch_bounds__(256) void wconv_kernel(
    const float4* __restrict__ w1, const float4* __restrict__ w2,
    const float4* __restrict__ w3, u16* __restrict__ wtAll, u32* __restrict__ tzero,
    const int* __restrict__ degHist, int* __restrict__ degCursor)
{
    int tid = threadIdx.x;
    if (blockIdx.x == 3) {
        if (tid < 64) tzero[tid] = 0;   // zero row (index N) of T table: 128 bf16 = 64 u32
        return;
    }
    if (blockIdx.x == 4) {
        // reverse-order exclusive scan of 16 bins: heavy rows get lowest positions
        if (tid == 0) {
            int base = 0;
            for (int k = 15; k >= 0; --k) {
                degCursor[k * 16] = base;
                base += degHist[k * 16];
            }
        }
        return;
    }
    const float4* W = (blockIdx.x == 0) ? w1 : (blockIdx.x == 1) ? w2 : w3;
    u16* Wt = wtAll + (size_t)blockIdx.x * D * D;
#pragma unroll
    for (int i = 0; i < 16; ++i) {
        int idx = tid + i * 256;        // = k*32 + c4
        int k = idx >> 5, c4 = idx & 31;
        float4 v = W[idx];
        Wt[(4 * c4 + 0) * D + k] = f2bf(v.x);
        Wt[(4 * c4 + 1) * D + k] = f2bf(v.y);
        Wt[(4 * c4 + 2) * D + k] = f2bf(v.z);
        Wt[(4 * c4 + 3) * D + k] = f2bf(v.w);
    }
}

// ---- degree-sorted permutation: hierarchical counting-sort scatter ----
__global__ __launch_bounds__(256) void perm_scatter_kernel(
    const int* __restrict__ rowPtr, int* __restrict__ degCursor,
    int* __restrict__ perm, int N)
{
    __shared__ int lh[16], lbase[16];
    int tid = threadIdx.x;
    if (tid < 16) lh[tid] = 0;
    __syncthreads();
    int v = blockIdx.x * 256 + tid;
    int key = 0, r = 0;
    bool ok = (v < N);
    if (ok) {
        int deg = rowPtr[v + 1] - rowPtr[v];
        key = (deg + 15) >> 4;
        if (key > 15) key = 15;
        r = atomicAdd(&lh[key], 1);
    }
    __syncthreads();
    if (tid < 16 && lh[tid] > 0) lbase[tid] = atomicAdd(&degCursor[tid * 16], lh[tid]);
    __syncthreads();
    if (ok) perm[lbase[key] + r] = v;
}

// ---------------- MFMA GEMM core (A=W frag, B=X frag; 8B stores) ----------------
// Epilogue pre-scales the output row by dinv[row]: T'[u] = dinv[u] * (X W)[u].
#define XS_STRIDE 136
#define GEMM_GRID 768

__device__ __forceinline__ void gemm_core_and_store(
    const u16* Xs, const u16* Ws, const float* __restrict__ dinv,
    u16* __restrict__ Y, int row0, int nrows, int tid)
{
    int wid = tid >> 6, lane = tid & 63;
    int m = lane & 15, quad = lane >> 4;
    int xrow = wid * 16 + m;

    floatx4 acc[8] = {};
#pragma unroll
    for (int ks = 0; ks < 4; ++ks) {
        int kk = ks * 32 + quad * 8;
        B8 a;
        a.u = *(const ushort8_t*)&Xs[xrow * XS_STRIDE + kk];
#pragma unroll
        for (int t = 0; t < 8; ++t) {
            B8 b;
            b.u = *(const ushort8_t*)&Ws[(t * 16 + m) * XS_STRIDE + kk];
            acc[t] = __builtin_amdgcn_mfma_f32_16x16x32_bf16(b.b, a.b, acc[t], 0, 0, 0);
        }
    }
    int grow = row0 + xrow;
    if (grow < nrows) {
        float du = dinv[grow];
#pragma unroll
        for (int t = 0; t < 8; ++t) {
            ushort4_t o;
            o.x = f2bf(acc[t][0] * du); o.y = f2bf(acc[t][1] * du);
            o.z = f2bf(acc[t][2] * du); o.w = f2bf(acc[t][3] * du);
            *(ushort4_t*)&Y[(size_t)grow * D + t * 16 + quad * 4] = o;
        }
    }
}

__device__ __forceinline__ void stage_w(const u16* __restrict__ Wt, u16* Ws, int tid) {
    const ushort8_t* Wv = (const ushort8_t*)Wt;
#pragma unroll
    for (int i = 0; i < 8; ++i) {
        int idx = tid + i * 256;        // = n*16 + c8
        int n = idx >> 4, c8 = idx & 15;
        *(ushort8_t*)&Ws[n * XS_STRIDE + c8 * 8] = Wv[idx];
    }
}

// layer 1: X fp32, persistent tiles
__global__ __launch_bounds__(256) void gemm_mfma_f32in_kernel(
    const float4* __restrict__ X, const u16* __restrict__ Wt,
    const float* __restrict__ dinv, u16* __restrict__ Y, int nrows, int ntiles)
{
    __shared__ __align__(16) u16 Xs[64 * XS_STRIDE];
    __shared__ __align__(16) u16 Ws[128 * XS_STRIDE];
    int tid = threadIdx.x;
    stage_w(Wt, Ws, tid);
    for (int t = blockIdx.x; t < ntiles; t += gridDim.x) {
        int row0 = t * 64;
        __syncthreads();   // Ws ready / prev tile's reads done
#pragma unroll
        for (int i = 0; i < 8; ++i) {
            int idx = tid + i * 256;        // = r*32 + c4
            int r = idx >> 5, c4 = idx & 31;
            int gr = row0 + r;
            float4 v = make_float4(0.f, 0.f, 0.f, 0.f);
            if (gr < nrows) v = X[(size_t)gr * 32 + c4];
            ushort4_t o;
            o.x = f2bf(v.x); o.y = f2bf(v.y); o.z = f2bf(v.z); o.w = f2bf(v.w);
            *(ushort4_t*)&Xs[r * XS_STRIDE + c4 * 4] = o;
        }
        __syncthreads();
        gemm_core_and_store(Xs, Ws, dinv, Y, row0, nrows, tid);
    }
}

// layers 2/3: X bf16, optional fused bn(from raw stats)+relu on input, persistent
__global__ __launch_bounds__(256) void gemm_mfma_bf16in_kernel(
    const uint4* __restrict__ X, const u16* __restrict__ Wt,
    const float* __restrict__ gsum, const float* __restrict__ gsq,
    const float* __restrict__ gamma, const float* __restrict__ beta, float invN,
    const float* __restrict__ dinv, u16* __restrict__ Y, int nrows, int ntiles)
{
    __shared__ __align__(16) u16 Xs[64 * XS_STRIDE];
    __shared__ __align__(16) u16 Ws[128 * XS_STRIDE];
    __shared__ float scs[D], shs[D];
    int tid = threadIdx.x;
    bool fuse = (gsum != nullptr);
    stage_w(Wt, Ws, tid);
    if (fuse && tid < D) {
        float mu = gsum[tid] * invN;
        float var = gsq[tid] * invN - mu * mu;
        float sc = gamma[tid] * rsqrtf(var + BN_EPS);
        scs[tid] = sc;
        shs[tid] = beta[tid] - mu * sc;
    }
    for (int t = blockIdx.x; t < ntiles; t += gridDim.x) {
        int row0 = t * 64;
        __syncthreads();   // Ws/scs ready / prev tile's reads done
#pragma unroll
        for (int i = 0; i < 4; ++i) {
            int idx = tid + i * 256;        // = r*16 + c8
            int r = idx >> 4, c8 = idx & 15;
            int gr = row0 + r;
            uint4 v = make_uint4(0, 0, 0, 0);
            if (gr < nrows) v = X[(size_t)gr * 16 + c8];
            if (fuse) {
                int k = c8 * 8;
                v.x = pack2bf(fmaxf(bf_lo(v.x) * scs[k]     + shs[k],     0.f),
                              fmaxf(bf_hi(v.x) * scs[k + 1] + shs[k + 1], 0.f));
                v.y = pack2bf(fmaxf(bf_lo(v.y) * scs[k + 2] + shs[k + 2], 0.f),
                              fmaxf(bf_hi(v.y) * scs[k + 3] + shs[k + 3], 0.f));
                v.z = pack2bf(fmaxf(bf_lo(v.z) * scs[k + 4] + shs[k + 4], 0.f),
                              fmaxf(bf_hi(v.z) * scs[k + 5] + shs[k + 5], 0.f));
                v.w = pack2bf(fmaxf(bf_lo(v.w) * scs[k + 6] + shs[k + 6], 0.f),
                              fmaxf(bf_hi(v.w) * scs[k + 7] + shs[k + 7], 0.f));
            }
            *(uint4*)&Xs[r * XS_STRIDE + c8 * 8] = v;
        }
        __syncthreads();
        gemm_core_and_store(Xs, Ws, dinv, Y, row0, nrows, tid);
    }
}

// ---------------- aggregation v8 (verified 59us; at random-gather path ceiling) ----------
#define ACC8U(t)                                           \
    acc0 += bf_lo((t).x); acc1 += bf_hi((t).x);            \
    acc2 += bf_lo((t).y); acc3 += bf_hi((t).y);            \
    acc4 += bf_lo((t).z); acc5 += bf_hi((t).z);            \
    acc6 += bf_lo((t).w); acc7 += bf_hi((t).w);

#define IDX8(i, jj)                                        \
    i##0 = ci[(jj)];     i##1 = ci[(jj) + 1];              \
    i##2 = ci[(jj) + 2]; i##3 = ci[(jj) + 3];              \
    i##4 = ci[(jj) + 4]; i##5 = ci[(jj) + 5];              \
    i##6 = ci[(jj) + 6]; i##7 = ci[(jj) + 7];

#define OFF8(o, i, jj)                                     \
    o##0 = ((jj)     < len) ? ((u32)i##0 << 8) : zoff;     \
    o##1 = ((jj) + 1 < len) ? ((u32)i##1 << 8) : zoff;     \
    o##2 = ((jj) + 2 < len) ? ((u32)i##2 << 8) : zoff;     \
    o##3 = ((jj) + 3 < len) ? ((u32)i##3 << 8) : zoff;     \
    o##4 = ((jj) + 4 < len) ? ((u32)i##4 << 8) : zoff;     \
    o##5 = ((jj) + 5 < len) ? ((u32)i##5 << 8) : zoff;     \
    o##6 = ((jj) + 6 < len) ? ((u32)i##6 << 8) : zoff;     \
    o##7 = ((jj) + 7 < len) ? ((u32)i##7 << 8) : zoff;

#define GAT8(t, o)                                         \
    t##0 = *(const uint4*)(baseT + o##0);                  \
    t##1 = *(const uint4*)(baseT + o##1);                  \
    t##2 = *(const uint4*)(baseT + o##2);                  \
    t##3 = *(const uint4*)(baseT + o##3);                  \
    t##4 = *(const uint4*)(baseT + o##4);                  \
    t##5 = *(const uint4*)(baseT + o##5);                  \
    t##6 = *(const uint4*)(baseT + o##6);                  \
    t##7 = *(const uint4*)(baseT + o##7);

#define ACCC(t)                                            \
    ACC8U(t##0); ACC8U(t##1); ACC8U(t##2); ACC8U(t##3);    \
    ACC8U(t##4); ACC8U(t##5); ACC8U(t##6); ACC8U(t##7);

__global__ __launch_bounds__(256) void aggregate_kernel(
    const uint4* __restrict__ T, const int* __restrict__ colIdx,
    const int* __restrict__ rowPtr, const float* __restrict__ dinv,
    const float* __restrict__ bias, const int* __restrict__ perm,
    u32* __restrict__ outH, int n, u32 zoff)
{
    int tid = threadIdx.x;
    int fg = tid & 15;                 // feature group: 8 features = one uint4
    int grp = tid >> 4;                // 0..15: row slot within block
    int slot = blockIdx.x * 16 + grp;
    if (slot >= n) return;
    int row = perm[slot];

    const char* baseT = (const char*)T + fg * 16;

    // self loop (T' already carries dinv[row])
    uint4 sv = *(const uint4*)(baseT + ((size_t)(u32)row << 8));
    float acc0 = bf_lo(sv.x), acc1 = bf_hi(sv.x);
    float acc2 = bf_lo(sv.y), acc3 = bf_hi(sv.y);
    float acc4 = bf_lo(sv.z), acc5 = bf_hi(sv.z);
    float acc6 = bf_lo(sv.w), acc7 = bf_hi(sv.w);

    int s = rowPtr[row], e = rowPtr[row + 1];
    int len = e - s;
    const int* ci = colIdx + s;        // OOB reads (up to +24) land in pairs[] region: safe

    if (len > 0) {
        int npairs = (len + 15) >> 4;  // pairs of 8-edge chunks
        int ia0, ia1, ia2, ia3, ia4, ia5, ia6, ia7;
        int ib0, ib1, ib2, ib3, ib4, ib5, ib6, ib7;
        u32 oa0, oa1, oa2, oa3, oa4, oa5, oa6, oa7;
        u32 ob0, ob1, ob2, ob3, ob4, ob5, ob6, ob7;
        uint4 t0, t1, t2, t3, t4, t5, t6, t7;
        uint4 u0, u1, u2, u3, u4, u5, u6, u7;

        IDX8(ia, 0); IDX8(ib, 8);
        OFF8(oa, ia, 0);
        GAT8(t, oa);
        OFF8(ob, ib, 8);
        IDX8(ia, 16);
        GAT8(u, ob);

#pragma unroll 1
        for (int p = 1; p < npairs; ++p) {
            int j = p << 4;
            OFF8(oa, ia, j);
            IDX8(ib, j + 8);
            ACCC(t);
            GAT8(t, oa);
            OFF8(ob, ib, j + 8);
            ACCC(u);
            IDX8(ia, j + 16);
            GAT8(u, ob);
        }
        ACCC(t); ACCC(u);
    }

    float dr = dinv[row];
    const float2* bp = (const float2*)bias;   // feature pairs fg*4 .. fg*4+3
    float2 bq0 = bp[fg * 4 + 0];
    float2 bq1 = bp[fg * 4 + 1];
    float2 bq2 = bp[fg * 4 + 2];
    float2 bq3 = bp[fg * 4 + 3];
    uint4 o;
    o.x = pack2bf(fmaxf(dr * acc0 + bq0.x, 0.f), fmaxf(dr * acc1 + bq0.y, 0.f));
    o.y = pack2bf(fmaxf(dr * acc2 + bq1.x, 0.f), fmaxf(dr * acc3 + bq1.y, 0.f));
    o.z = pack2bf(fmaxf(dr * acc4 + bq2.x, 0.f), fmaxf(dr * acc5 + bq2.y, 0.f));
    o.w = pack2bf(fmaxf(dr * acc6 + bq3.x, 0.f), fmaxf(dr * acc7 + bq3.y, 0.f));
    *(uint4*)&outH[(size_t)row * 64 + fg * 4] = o;
}

// ---------------- batchnorm stats v2: partial buffer + last-block reduce --------------
// Round-5 lesson: the old 1024-block version ended with 262k device-scope f32 atomics
// on 16 cache lines (gsum/gsq) -> cross-XCD line serialization ~tens of us hidden cost.
// Now: each block writes 256 partial floats to a private slot (no contention), one
// ticket atomic per block; last block reduces all partials and writes gsum/gsq.
__global__ __launch_bounds__(256) void bn_stats_kernel(
    const u32* __restrict__ H, int n, float* __restrict__ partials,
    int* __restrict__ ticket, float* __restrict__ gsum, float* __restrict__ gsq)
{
    int tid = threadIdx.x;
    int c = tid & 63, rr = tid >> 6;
    float sA = 0.f, sA2 = 0.f, sB = 0.f, sB2 = 0.f;
    for (int row = blockIdx.x * 4 + rr; row < n; row += BN_BLOCKS * 4) {
        u32 v = H[(size_t)row * 64 + c];
        float a = bf_lo(v), b = bf_hi(v);
        sA += a; sA2 += a * a; sB += b; sB2 += b * b;
    }
    __shared__ float shA[256], shA2[256], shB[256], shB2[256];
    shA[tid] = sA; shA2[tid] = sA2; shB[tid] = sB; shB2[tid] = sB2;
    __syncthreads();
    if (tid < 64) {
        float tA = shA[tid] + shA[tid + 64] + shA[tid + 128] + shA[tid + 192];
        float tA2 = shA2[tid] + shA2[tid + 64] + shA2[tid + 128] + shA2[tid + 192];
        float tB = shB[tid] + shB[tid + 64] + shB[tid + 128] + shB[tid + 192];
        float tB2 = shB2[tid] + shB2[tid + 64] + shB2[tid + 128] + shB2[tid + 192];
        float* pb = partials + (size_t)blockIdx.x * 256;
        pb[tid] = tA; pb[64 + tid] = tA2; pb[128 + tid] = tB; pb[192 + tid] = tB2;
    }
    __threadfence();
    __shared__ int lastFlag;
    if (tid == 0) lastFlag = (atomicAdd(ticket, 1) == BN_BLOCKS - 1);
    __syncthreads();
    if (!lastFlag) return;
    __threadfence();
    // last block: thread j sums partials[b*256 + j] over all b
    float a0 = 0.f, a1 = 0.f, a2 = 0.f, a3 = 0.f;
    const float* pj = partials + tid;
#pragma unroll 4
    for (int b = 0; b < BN_BLOCKS; b += 4) {
        a0 += pj[(size_t)(b + 0) * 256];
        a1 += pj[(size_t)(b + 1) * 256];
        a2 += pj[(size_t)(b + 2) * 256];
        a3 += pj[(size_t)(b + 3) * 256];
    }
    float acc = (a0 + a1) + (a2 + a3);
    int j = tid;
    if (j < 64)       gsum[2 * j] = acc;
    else if (j < 128) gsq[2 * (j - 64)] = acc;
    else if (j < 192) gsum[2 * (j - 128) + 1] = acc;
    else              gsq[2 * (j - 192) + 1] = acc;
}

// ---------------- pool (bn2 from raw stats + relu) + classify + log_softmax ----------------
__global__ __launch_bounds__(256) void pool_classify_kernel(
    const u32* __restrict__ H, const float* __restrict__ gsum, const float* __restrict__ gsq,
    const float* __restrict__ gamma, const float* __restrict__ beta, float invN,
    const int* __restrict__ gstart, const float* __restrict__ fcw,
    const float* __restrict__ fcb, float* __restrict__ out)
{
    int g = blockIdx.x;
    int tid = threadIdx.x;
    int c = tid & 63, q = tid >> 6;
    // bn2 scale/shift for features 2c, 2c+1 (redundant across q — cheap)
    float muA = gsum[2 * c] * invN, muB = gsum[2 * c + 1] * invN;
    float vA = gsq[2 * c] * invN - muA * muA, vB = gsq[2 * c + 1] * invN - muB * muB;
    float scA = gamma[2 * c] * rsqrtf(vA + BN_EPS), scB = gamma[2 * c + 1] * rsqrtf(vB + BN_EPS);
    float shA = beta[2 * c] - muA * scA, shB = beta[2 * c + 1] - muB * scB;

    int s = gstart[g], cnt = gstart[g + 1] - s;
    float aA = 0.f, aB = 0.f;
    for (int i = q; i < cnt; i += 4) {
        u32 v = H[(size_t)(s + i) * 64 + c];
        aA += fmaxf(bf_lo(v) * scA + shA, 0.f);
        aB += fmaxf(bf_hi(v) * scB + shB, 0.f);
    }
    __shared__ float sA[256], sB[256];
    __shared__ float prow[D];
    __shared__ float lg[C_CLASSES];
    sA[tid] = aA; sB[tid] = aB;
    __syncthreads();
    if (tid < 64) {
        float tA = sA[tid] + sA[tid + 64] + sA[tid + 128] + sA[tid + 192];
        float tB = sB[tid] + sB[tid + 64] + sB[tid + 128] + sB[tid + 192];
        float inv = 1.f / (float)(cnt > 1 ? cnt : 1);
        prow[2 * tid] = tA * inv;
        prow[2 * tid + 1] = tB * inv;
    }
    __syncthreads();
    if (tid < C_CLASSES) {
        float sum = fcb[tid];
        for (int d = 0; d < D; ++d) sum += prow[d] * fcw[d * C_CLASSES + tid];
        lg[tid] = sum;
    }
    __syncthreads();
    if (tid == 0) {
        float mx = -1e30f;
        for (int k = 0; k < C_CLASSES; ++k) mx = fmaxf(mx, lg[k]);
        float se = 0.f;
        for (int k = 0; k < C_CLASSES; ++k) se += expf(lg[k] - mx);
        float lse = mx + logf(se);
        for (int k = 0; k < C_CLASSES; ++k) out[(size_t)g * C_CLASSES + k] = lg[k] - lse;
    }
}

extern "C" void kernel_launch(void* const* d_in, const int* in_sizes, int n_in,
                              void* d_out, int out_size, void* d_ws, size_t ws_size,
                              hipStream_t stream) {
    const float* x   = (const float*)d_in[0];
    const int* ei    = (const int*)d_in[1];
    const int* batch = (const int*)d_in[2];
    const float* w1  = (const float*)d_in[3];
    const float* b1  = (const float*)d_in[4];
    const float* w2  = (const float*)d_in[5];
    const float* b2  = (const float*)d_in[6];
    const float* w3  = (const float*)d_in[7];
    const float* b3  = (const float*)d_in[8];
    const float* g1  = (const float*)d_in[9];
    const float* be1 = (const float*)d_in[10];
    const float* g2  = (const float*)d_in[11];
    const float* be2 = (const float*)d_in[12];
    const float* fcw = (const float*)d_in[13];
    const float* fcb = (const float*)d_in[14];

    const int N = in_sizes[0] / D;
    const int E = in_sizes[1] / 2;
    const int* src = ei;
    const int* dst = ei + E;
    const int nbuck = (N + 255) >> 8;
    const float invN = 1.f / (float)N;

    char* p = (char*)d_ws;
    auto alloc = [&](size_t bytes) -> void* {
        void* r = (void*)p;
        p += (bytes + 255) & ~(size_t)255;
        return r;
    };
    // memset span: bucketCnt(2048) + statsacc(2048) + degHist(2048) + bnTick(256)
    int*   bucketCnt    = (int*)alloc(NBUCK_MAX * 4);
    float* statsacc     = (float*)alloc(4 * D * 4);
    float* gsum1 = statsacc, *gsq1 = statsacc + D, *gsum2 = statsacc + 2 * D, *gsq2 = statsacc + 3 * D;
    int*   degHist      = (int*)alloc(2 * 16 * 16 * 4);   // 16 bins @ 64B stride + 16 cursors
    int*   degCursor    = degHist + 256;
    int*   bnTick       = (int*)alloc(256);               // bnTick[0], bnTick[16]
    float* dinv     = (float*)alloc((size_t)N * 4);
    int*   rowPtr   = (int*)alloc((size_t)(N + 1) * 4);
    int*   colIdx   = (int*)alloc((size_t)E * 4);
    u32*   pairs    = (u32*)alloc((size_t)E * 4);   // must follow colIdx (OOB-read slack)
    int*   bucketBase   = (int*)alloc((NBUCK_MAX + 1) * 4);
    int*   bucketCursor = (int*)alloc(NBUCK_MAX * 4);
    int*   gstart  = (int*)alloc((G_GRAPHS + 1) * 4);
    int*   perm    = (int*)alloc((size_t)N * 4);
    float* bnPart  = (float*)alloc((size_t)BN_BLOCKS * 256 * 4);   // 512KB partials
    u16*   wtAll   = (u16*)alloc((size_t)3 * D * D * 2);       // bf16 W^T x3
    u16*   tmp     = (u16*)alloc((size_t)(N + 1) * D * 2);     // bf16 gemm out + zero row N
    u16*   hbuf    = (u16*)alloc((size_t)N * D * 2);           // bf16 agg out

    hipMemsetAsync(bucketCnt, 0, NBUCK_MAX * 4 + 4 * D * 4 + 2 * 16 * 16 * 4 + 256, stream);

    // ---- graph structure (graph_bounds folded into bucket_hist: blocks >= 512) ----
    bucket_hist_kernel<<<HIST_BLOCKS + (N + 255) / 256, 256, 0, stream>>>(
        dst, bucketCnt, E, nbuck, batch, gstart, N);
    scan_buckets_kernel<<<1, 512, 0, stream>>>(bucketCnt, bucketBase, bucketCursor, rowPtr, nbuck, N, E);
    scatter_pairs_kernel<<<(E + EDGE_CHUNK - 1) / EDGE_CHUNK, 256, 0, stream>>>(src, dst, bucketCursor, pairs, E);
    bucket_sort_kernel<<<nbuck, 256, 0, stream>>>(pairs, bucketBase, colIdx, rowPtr, dinv, degHist, N);
    wconv_kernel<<<5, 256, 0, stream>>>((const float4*)w1, (const float4*)w2, (const float4*)w3,
                                        wtAll, (u32*)(tmp + (size_t)N * D), degHist, degCursor);
    perm_scatter_kernel<<<(N + 255) / 256, 256, 0, stream>>>(rowPtr, degCursor, perm, N);

    const int NT = (N + 63) / 64;            // gemm tiles
    const int GB = NT < GEMM_GRID ? NT : GEMM_GRID;
    const int AB = (N + 15) / 16;            // aggregate blocks: 16 rows/block
    const u32 ZOFF = (u32)N << 8;            // byte offset of zero row

    gemm_mfma_f32in_kernel<<<GB, 256, 0, stream>>>((const float4*)x, wtAll, dinv, tmp, N, NT);
    aggregate_kernel<<<AB, 256, 0, stream>>>((const uint4*)tmp, colIdx, rowPtr, dinv, b1, perm, (u32*)hbuf, N, ZOFF);
    gemm_mfma_bf16in_kernel<<<GB, 256, 0, stream>>>((const uint4*)hbuf, wtAll + D * D,
        nullptr, nullptr, nullptr, nullptr, 0.f, dinv, tmp, N, NT);
    aggregate_kernel<<<AB, 256, 0, stream>>>((const uint4*)tmp, colIdx, rowPtr, dinv, b2, perm, (u32*)hbuf, N, ZOFF);
    bn_stats_kernel<<<BN_BLOCKS, 256, 0, stream>>>((const u32*)hbuf, N, bnPart, bnTick, gsum1, gsq1);
    gemm_mfma_bf16in_kernel<<<GB, 256, 0, stream>>>((const uint4*)hbuf, wtAll + 2 * D * D,
        gsum1, gsq1, g1, be1, invN, dinv, tmp, N, NT);
    aggregate_kernel<<<AB, 256, 0, stream>>>((const uint4*)tmp, colIdx, rowPtr, dinv, b3, perm, (u32*)hbuf, N, ZOFF);
    bn_stats_kernel<<<BN_BLOCKS, 256, 0, stream>>>((const u32*)hbuf, N, bnPart, bnTick + 16, gsum2, gsq2);
    pool_classify_kernel<<<G_GRAPHS, 256, 0, stream>>>((const u32*)hbuf, gsum2, gsq2, g2, be2, invN,
        gstart, fcw, fcb, (float*)d_out);
}

// Round 7
// 524.259 us; speedup vs baseline: 1.0649x; 1.0649x over previous
//
#include <hip/hip_runtime.h>
#include <hip/hip_bf16.h>
#include <math.h>

#define D 128
#define G_GRAPHS 512
#define C_CLASSES 10
#define BN_EPS 1e-5f
#define NBUCK_MAX 512     // supports N <= 131072 (bucket = node >> 8)
#define EDGE_CHUNK 4096
#define EPT 16            // EDGE_CHUNK / 256
#define HIST_BLOCKS 512
#define BN_BLOCKS 512

typedef unsigned short u16;
typedef unsigned int u32;
typedef unsigned short ushort4_t __attribute__((ext_vector_type(4)));
typedef unsigned short ushort8_t __attribute__((ext_vector_type(8)));
typedef __bf16 bf16x8 __attribute__((ext_vector_type(8)));
typedef float floatx4 __attribute__((ext_vector_type(4)));
union B8 { ushort8_t u; bf16x8 b; };

__device__ __forceinline__ float bf_lo(u32 v) { return __uint_as_float(v << 16); }
__device__ __forceinline__ float bf_hi(u32 v) { return __uint_as_float(v & 0xffff0000u); }
__device__ __forceinline__ u16 f2bf(float f) {
    union { float f; u32 u; } x; x.f = f;
    u32 r = x.u + 0x7fff + ((x.u >> 16) & 1);  // RN-even
    return (u16)(r >> 16);
}
__device__ __forceinline__ u32 pack2bf(float a, float b) {
    return (u32)f2bf(a) | ((u32)f2bf(b) << 16);
}

// ============ CSR build: two-level counting sort ============
// blocks >= HIST_BLOCKS run the graph-bounds body (launch fusion)

__global__ __launch_bounds__(256) void bucket_hist_kernel(
    const int* __restrict__ dst, int* __restrict__ bucketCnt, int E, int nbuck,
    const int* __restrict__ batch, int* __restrict__ gstart, int N)
{
    int tid = threadIdx.x;
    if (blockIdx.x >= HIST_BLOCKS) {
        // ---- graph segments: boundary detection on sorted batch ----
        int i = (blockIdx.x - HIST_BLOCKS) * 256 + tid;
        if (i >= N) return;
        int b = batch[i];
        int prev = (i == 0) ? -1 : batch[i - 1];
        if (b != prev) {
            for (int g = prev + 1; g <= b; ++g) gstart[g] = i;  // covers empty graphs
        }
        if (i == N - 1) {
            for (int g = b + 1; g <= G_GRAPHS; ++g) gstart[g] = N;
        }
        return;
    }
    __shared__ int h[NBUCK_MAX];
    for (int i = tid; i < NBUCK_MAX; i += 256) h[i] = 0;
    __syncthreads();
    for (int i = blockIdx.x * 256 + tid; i < E; i += HIST_BLOCKS * 256)
        atomicAdd(&h[dst[i] >> 8], 1);
    __syncthreads();
    for (int i = tid; i < nbuck; i += 256)
        if (h[i]) atomicAdd(&bucketCnt[i], h[i]);
}

__global__ void scan_buckets_kernel(
    const int* __restrict__ bucketCnt, int* __restrict__ bucketBase,
    int* __restrict__ bucketCursor, int* __restrict__ rowPtr, int nbuck, int N, int E)
{
    __shared__ int buf[2][512];
    int tid = threadIdx.x;
    int v = (tid < nbuck) ? bucketCnt[tid] : 0;
    buf[0][tid] = v;
    __syncthreads();
    int cur = 0;
    for (int off = 1; off < 512; off <<= 1) {
        buf[1 - cur][tid] = buf[cur][tid] + ((tid >= off) ? buf[cur][tid - off] : 0);
        cur ^= 1;
        __syncthreads();
    }
    if (tid < nbuck) {
        int b = buf[cur][tid] - v;  // exclusive
        bucketBase[tid] = b;
        bucketCursor[tid] = b;
    }
    if (tid == 0) { bucketBase[nbuck] = E; rowPtr[N] = E; }
}

// pairs packed: (src << 8) | (dst & 255)   [src < 2^17, fits 25 bits]
__global__ __launch_bounds__(256) void scatter_pairs_kernel(
    const int* __restrict__ src, const int* __restrict__ dst,
    int* __restrict__ bucketCursor, u32* __restrict__ pairs, int E)
{
    __shared__ int h[NBUCK_MAX];
    __shared__ int base[NBUCK_MAX];
    int tid = threadIdx.x;
    int e0 = blockIdx.x * EDGE_CHUNK;
    for (int i = tid; i < NBUCK_MAX; i += 256) h[i] = 0;
    __syncthreads();
    int s[EPT], d[EPT], r[EPT];
#pragma unroll
    for (int j = 0; j < EPT; ++j) {
        int i = e0 + j * 256 + tid;
        if (i < E) {
            s[j] = src[i];
            d[j] = dst[i];
            r[j] = atomicAdd(&h[d[j] >> 8], 1);
        } else {
            d[j] = -1;
        }
    }
    __syncthreads();
    for (int i = tid; i < NBUCK_MAX; i += 256)
        if (h[i]) base[i] = atomicAdd(&bucketCursor[i], h[i]);
    __syncthreads();
#pragma unroll
    for (int j = 0; j < EPT; ++j) {
        if (d[j] >= 0) {
            int b = d[j] >> 8;
            pairs[base[b] + r[j]] = ((u32)s[j] << 8) | (u32)(d[j] & 255);
        }
    }
}

// degHist/degCursor: 16 bins, each padded to its own 64B line (stride 16 ints)
__global__ __launch_bounds__(256) void bucket_sort_kernel(
    const u32* __restrict__ pairs, const int* __restrict__ bucketBase,
    int* __restrict__ colIdx, int* __restrict__ rowPtr, float* __restrict__ dinv,
    int* __restrict__ degHist, int N)
{
    __shared__ int h[256];
    __shared__ int cur[256];
    __shared__ int sbuf[2][256];
    __shared__ int dh[16];
    int tid = threadIdx.x;
    int b = blockIdx.x;
    int s = bucketBase[b], e = bucketBase[b + 1];
    h[tid] = 0;
    if (tid < 16) dh[tid] = 0;
    __syncthreads();
    for (int i = s + tid; i < e; i += 256)
        atomicAdd(&h[pairs[i] & 255], 1);
    __syncthreads();
    int cnt = h[tid];
    sbuf[0][tid] = cnt;
    __syncthreads();
    int c = 0;
    for (int off = 1; off < 256; off <<= 1) {
        sbuf[1 - c][tid] = sbuf[c][tid] + ((tid >= off) ? sbuf[c][tid - off] : 0);
        c ^= 1;
        __syncthreads();
    }
    int excl = sbuf[c][tid] - cnt;
    int v = b * 256 + tid;
    if (v < N) {
        rowPtr[v] = s + excl;
        dinv[v] = rsqrtf((float)(cnt + 1));  // +1 self loop
        int key = (cnt + 15) >> 4;           // cost bin = pair count
        if (key > 15) key = 15;
        atomicAdd(&dh[key], 1);              // LDS-local (round-4 lesson: 100k
                                             // same-line global atomics = 788us)
    }
    cur[tid] = s + excl;
    __syncthreads();
    if (tid < 16 && dh[tid]) atomicAdd(&degHist[tid * 16], dh[tid]);  // 16 flushes/block
    for (int i = s + tid; i < e; i += 256) {
        u32 p = pairs[i];
        int pos = atomicAdd(&cur[p & 255], 1);
        colIdx[pos] = (int)(p >> 8);
    }
}

// ---- W pre-transpose+convert; block 3 zeroes T row N; block 4 scans deg bins ----
__global__ __launch_bounds__(256) void wconv_kernel(
    const float4* __restrict__ w1, const float4* __restrict__ w2,
    const float4* __restrict__ w3, u16* __restrict__ wtAll, u32* __restrict__ tzero,
    const int* __restrict__ degHist, int* __restrict__ degCursor)
{
    int tid = threadIdx.x;
    if (blockIdx.x == 3) {
        if (tid < 64) tzero[tid] = 0;   // zero row (index N) of T table: 128 bf16 = 64 u32
        return;
    }
    if (blockIdx.x == 4) {
        // reverse-order exclusive scan of 16 bins: heavy rows get lowest positions
        if (tid == 0) {
            int base = 0;
            for (int k = 15; k >= 0; --k) {
                degCursor[k * 16] = base;
                base += degHist[k * 16];
            }
        }
        return;
    }
    const float4* W = (blockIdx.x == 0) ? w1 : (blockIdx.x == 1) ? w2 : w3;
    u16* Wt = wtAll + (size_t)blockIdx.x * D * D;
#pragma unroll
    for (int i = 0; i < 16; ++i) {
        int idx = tid + i * 256;        // = k*32 + c4
        int k = idx >> 5, c4 = idx & 31;
        float4 v = W[idx];
        Wt[(4 * c4 + 0) * D + k] = f2bf(v.x);
        Wt[(4 * c4 + 1) * D + k] = f2bf(v.y);
        Wt[(4 * c4 + 2) * D + k] = f2bf(v.z);
        Wt[(4 * c4 + 3) * D + k] = f2bf(v.w);
    }
}

// ---- degree-sorted permutation: hierarchical counting-sort scatter ----
__global__ __launch_bounds__(256) void perm_scatter_kernel(
    const int* __restrict__ rowPtr, int* __restrict__ degCursor,
    int* __restrict__ perm, int N)
{
    __shared__ int lh[16], lbase[16];
    int tid = threadIdx.x;
    if (tid < 16) lh[tid] = 0;
    __syncthreads();
    int v = blockIdx.x * 256 + tid;
    int key = 0, r = 0;
    bool ok = (v < N);
    if (ok) {
        int deg = rowPtr[v + 1] - rowPtr[v];
        key = (deg + 15) >> 4;
        if (key > 15) key = 15;
        r = atomicAdd(&lh[key], 1);
    }
    __syncthreads();
    if (tid < 16 && lh[tid] > 0) lbase[tid] = atomicAdd(&degCursor[tid * 16], lh[tid]);
    __syncthreads();
    if (ok) perm[lbase[key] + r] = v;
}

// ---------------- MFMA GEMM core (A=W frag, B=X frag; 8B stores) ----------------
// Epilogue pre-scales the output row by dinv[row]: T'[u] = dinv[u] * (X W)[u].
#define XS_STRIDE 136
#define GEMM_GRID 768

__device__ __forceinline__ void gemm_core_and_store(
    const u16* Xs, const u16* Ws, const float* __restrict__ dinv,
    u16* __restrict__ Y, int row0, int nrows, int tid)
{
    int wid = tid >> 6, lane = tid & 63;
    int m = lane & 15, quad = lane >> 4;
    int xrow = wid * 16 + m;

    floatx4 acc[8] = {};
#pragma unroll
    for (int ks = 0; ks < 4; ++ks) {
        int kk = ks * 32 + quad * 8;
        B8 a;
        a.u = *(const ushort8_t*)&Xs[xrow * XS_STRIDE + kk];
#pragma unroll
        for (int t = 0; t < 8; ++t) {
            B8 b;
            b.u = *(const ushort8_t*)&Ws[(t * 16 + m) * XS_STRIDE + kk];
            acc[t] = __builtin_amdgcn_mfma_f32_16x16x32_bf16(b.b, a.b, acc[t], 0, 0, 0);
        }
    }
    int grow = row0 + xrow;
    if (grow < nrows) {
        float du = dinv[grow];
#pragma unroll
        for (int t = 0; t < 8; ++t) {
            ushort4_t o;
            o.x = f2bf(acc[t][0] * du); o.y = f2bf(acc[t][1] * du);
            o.z = f2bf(acc[t][2] * du); o.w = f2bf(acc[t][3] * du);
            *(ushort4_t*)&Y[(size_t)grow * D + t * 16 + quad * 4] = o;
        }
    }
}

__device__ __forceinline__ void stage_w(const u16* __restrict__ Wt, u16* Ws, int tid) {
    const ushort8_t* Wv = (const ushort8_t*)Wt;
#pragma unroll
    for (int i = 0; i < 8; ++i) {
        int idx = tid + i * 256;        // = n*16 + c8
        int n = idx >> 4, c8 = idx & 15;
        *(ushort8_t*)&Ws[n * XS_STRIDE + c8 * 8] = Wv[idx];
    }
}

// layer 1: X fp32, persistent tiles
__global__ __launch_bounds__(256) void gemm_mfma_f32in_kernel(
    const float4* __restrict__ X, const u16* __restrict__ Wt,
    const float* __restrict__ dinv, u16* __restrict__ Y, int nrows, int ntiles)
{
    __shared__ __align__(16) u16 Xs[64 * XS_STRIDE];
    __shared__ __align__(16) u16 Ws[128 * XS_STRIDE];
    int tid = threadIdx.x;
    stage_w(Wt, Ws, tid);
    for (int t = blockIdx.x; t < ntiles; t += gridDim.x) {
        int row0 = t * 64;
        __syncthreads();   // Ws ready / prev tile's reads done
#pragma unroll
        for (int i = 0; i < 8; ++i) {
            int idx = tid + i * 256;        // = r*32 + c4
            int r = idx >> 5, c4 = idx & 31;
            int gr = row0 + r;
            float4 v = make_float4(0.f, 0.f, 0.f, 0.f);
            if (gr < nrows) v = X[(size_t)gr * 32 + c4];
            ushort4_t o;
            o.x = f2bf(v.x); o.y = f2bf(v.y); o.z = f2bf(v.z); o.w = f2bf(v.w);
            *(ushort4_t*)&Xs[r * XS_STRIDE + c4 * 4] = o;
        }
        __syncthreads();
        gemm_core_and_store(Xs, Ws, dinv, Y, row0, nrows, tid);
    }
}

// layers 2/3: X bf16, optional fused bn(from raw stats)+relu on input, persistent
__global__ __launch_bounds__(256) void gemm_mfma_bf16in_kernel(
    const uint4* __restrict__ X, const u16* __restrict__ Wt,
    const float* __restrict__ gsum, const float* __restrict__ gsq,
    const float* __restrict__ gamma, const float* __restrict__ beta, float invN,
    const float* __restrict__ dinv, u16* __restrict__ Y, int nrows, int ntiles)
{
    __shared__ __align__(16) u16 Xs[64 * XS_STRIDE];
    __shared__ __align__(16) u16 Ws[128 * XS_STRIDE];
    __shared__ float scs[D], shs[D];
    int tid = threadIdx.x;
    bool fuse = (gsum != nullptr);
    stage_w(Wt, Ws, tid);
    if (fuse && tid < D) {
        float mu = gsum[tid] * invN;
        float var = gsq[tid] * invN - mu * mu;
        float sc = gamma[tid] * rsqrtf(var + BN_EPS);
        scs[tid] = sc;
        shs[tid] = beta[tid] - mu * sc;
    }
    for (int t = blockIdx.x; t < ntiles; t += gridDim.x) {
        int row0 = t * 64;
        __syncthreads();   // Ws/scs ready / prev tile's reads done
#pragma unroll
        for (int i = 0; i < 4; ++i) {
            int idx = tid + i * 256;        // = r*16 + c8
            int r = idx >> 4, c8 = idx & 15;
            int gr = row0 + r;
            uint4 v = make_uint4(0, 0, 0, 0);
            if (gr < nrows) v = X[(size_t)gr * 16 + c8];
            if (fuse) {
                int k = c8 * 8;
                v.x = pack2bf(fmaxf(bf_lo(v.x) * scs[k]     + shs[k],     0.f),
                              fmaxf(bf_hi(v.x) * scs[k + 1] + shs[k + 1], 0.f));
                v.y = pack2bf(fmaxf(bf_lo(v.y) * scs[k + 2] + shs[k + 2], 0.f),
                              fmaxf(bf_hi(v.y) * scs[k + 3] + shs[k + 3], 0.f));
                v.z = pack2bf(fmaxf(bf_lo(v.z) * scs[k + 4] + shs[k + 4], 0.f),
                              fmaxf(bf_hi(v.z) * scs[k + 5] + shs[k + 5], 0.f));
                v.w = pack2bf(fmaxf(bf_lo(v.w) * scs[k + 6] + shs[k + 6], 0.f),
                              fmaxf(bf_hi(v.w) * scs[k + 7] + shs[k + 7], 0.f));
            }
            *(uint4*)&Xs[r * XS_STRIDE + c8 * 8] = v;
        }
        __syncthreads();
        gemm_core_and_store(Xs, Ws, dinv, Y, row0, nrows, tid);
    }
}

// ---------------- aggregation v8 (verified 59us; at random-gather path ceiling) ----------
#define ACC8U(t)                                           \
    acc0 += bf_lo((t).x); acc1 += bf_hi((t).x);            \
    acc2 += bf_lo((t).y); acc3 += bf_hi((t).y);            \
    acc4 += bf_lo((t).z); acc5 += bf_hi((t).z);            \
    acc6 += bf_lo((t).w); acc7 += bf_hi((t).w);

#define IDX8(i, jj)                                        \
    i##0 = ci[(jj)];     i##1 = ci[(jj) + 1];              \
    i##2 = ci[(jj) + 2]; i##3 = ci[(jj) + 3];              \
    i##4 = ci[(jj) + 4]; i##5 = ci[(jj) + 5];              \
    i##6 = ci[(jj) + 6]; i##7 = ci[(jj) + 7];

#define OFF8(o, i, jj)                                     \
    o##0 = ((jj)     < len) ? ((u32)i##0 << 8) : zoff;     \
    o##1 = ((jj) + 1 < len) ? ((u32)i##1 << 8) : zoff;     \
    o##2 = ((jj) + 2 < len) ? ((u32)i##2 << 8) : zoff;     \
    o##3 = ((jj) + 3 < len) ? ((u32)i##3 << 8) : zoff;     \
    o##4 = ((jj) + 4 < len) ? ((u32)i##4 << 8) : zoff;     \
    o##5 = ((jj) + 5 < len) ? ((u32)i##5 << 8) : zoff;     \
    o##6 = ((jj) + 6 < len) ? ((u32)i##6 << 8) : zoff;     \
    o##7 = ((jj) + 7 < len) ? ((u32)i##7 << 8) : zoff;

#define GAT8(t, o)                                         \
    t##0 = *(const uint4*)(baseT + o##0);                  \
    t##1 = *(const uint4*)(baseT + o##1);                  \
    t##2 = *(const uint4*)(baseT + o##2);                  \
    t##3 = *(const uint4*)(baseT + o##3);                  \
    t##4 = *(const uint4*)(baseT + o##4);                  \
    t##5 = *(const uint4*)(baseT + o##5);                  \
    t##6 = *(const uint4*)(baseT + o##6);                  \
    t##7 = *(const uint4*)(baseT + o##7);

#define ACCC(t)                                            \
    ACC8U(t##0); ACC8U(t##1); ACC8U(t##2); ACC8U(t##3);    \
    ACC8U(t##4); ACC8U(t##5); ACC8U(t##6); ACC8U(t##7);

__global__ __launch_bounds__(256) void aggregate_kernel(
    const uint4* __restrict__ T, const int* __restrict__ colIdx,
    const int* __restrict__ rowPtr, const float* __restrict__ dinv,
    const float* __restrict__ bias, const int* __restrict__ perm,
    u32* __restrict__ outH, int n, u32 zoff)
{
    int tid = threadIdx.x;
    int fg = tid & 15;                 // feature group: 8 features = one uint4
    int grp = tid >> 4;                // 0..15: row slot within block
    int slot = blockIdx.x * 16 + grp;
    if (slot >= n) return;
    int row = perm[slot];

    const char* baseT = (const char*)T + fg * 16;

    // self loop (T' already carries dinv[row])
    uint4 sv = *(const uint4*)(baseT + ((size_t)(u32)row << 8));
    float acc0 = bf_lo(sv.x), acc1 = bf_hi(sv.x);
    float acc2 = bf_lo(sv.y), acc3 = bf_hi(sv.y);
    float acc4 = bf_lo(sv.z), acc5 = bf_hi(sv.z);
    float acc6 = bf_lo(sv.w), acc7 = bf_hi(sv.w);

    int s = rowPtr[row], e = rowPtr[row + 1];
    int len = e - s;
    const int* ci = colIdx + s;        // OOB reads (up to +24) land in pairs[] region: safe

    if (len > 0) {
        int npairs = (len + 15) >> 4;  // pairs of 8-edge chunks
        int ia0, ia1, ia2, ia3, ia4, ia5, ia6, ia7;
        int ib0, ib1, ib2, ib3, ib4, ib5, ib6, ib7;
        u32 oa0, oa1, oa2, oa3, oa4, oa5, oa6, oa7;
        u32 ob0, ob1, ob2, ob3, ob4, ob5, ob6, ob7;
        uint4 t0, t1, t2, t3, t4, t5, t6, t7;
        uint4 u0, u1, u2, u3, u4, u5, u6, u7;

        IDX8(ia, 0); IDX8(ib, 8);
        OFF8(oa, ia, 0);
        GAT8(t, oa);
        OFF8(ob, ib, 8);
        IDX8(ia, 16);
        GAT8(u, ob);

#pragma unroll 1
        for (int p = 1; p < npairs; ++p) {
            int j = p << 4;
            OFF8(oa, ia, j);
            IDX8(ib, j + 8);
            ACCC(t);
            GAT8(t, oa);
            OFF8(ob, ib, j + 8);
            ACCC(u);
            IDX8(ia, j + 16);
            GAT8(u, ob);
        }
        ACCC(t); ACCC(u);
    }

    float dr = dinv[row];
    const float2* bp = (const float2*)bias;   // feature pairs fg*4 .. fg*4+3
    float2 bq0 = bp[fg * 4 + 0];
    float2 bq1 = bp[fg * 4 + 1];
    float2 bq2 = bp[fg * 4 + 2];
    float2 bq3 = bp[fg * 4 + 3];
    uint4 o;
    o.x = pack2bf(fmaxf(dr * acc0 + bq0.x, 0.f), fmaxf(dr * acc1 + bq0.y, 0.f));
    o.y = pack2bf(fmaxf(dr * acc2 + bq1.x, 0.f), fmaxf(dr * acc3 + bq1.y, 0.f));
    o.z = pack2bf(fmaxf(dr * acc4 + bq2.x, 0.f), fmaxf(dr * acc5 + bq2.y, 0.f));
    o.w = pack2bf(fmaxf(dr * acc6 + bq3.x, 0.f), fmaxf(dr * acc7 + bq3.y, 0.f));
    *(uint4*)&outH[(size_t)row * 64 + fg * 4] = o;
}

// ---------------- batchnorm stats v3: vectorized stage1 + coalesced float4 tail --------
// Round-6 lesson: v2's last-block tail (512 serial scalar batches over 512KB) was 32us
// and stage1's 4B/thread loads ran at 775 GB/s. v3: stage1 reads uint4 (16B/lane,
// 16 rows x 16 quads per block), LDS-reduces 16 row-groups, writes 256 channel-major
// partials per block (no atomics). Last block reads partials as float4, 4 slots per
// iteration, fully coalesced and independent -> latency hidden.
__global__ __launch_bounds__(256) void bn_stats_kernel(
    const uint4* __restrict__ H4, int n, float* __restrict__ partials,
    int* __restrict__ ticket, float* __restrict__ gsum, float* __restrict__ gsq)
{
    int tid = threadIdx.x;
    int fg = tid & 15;                 // uint4 index within row (8 channels)
    int grp = tid >> 4;                // row slot 0..15
    float s0 = 0.f, s1 = 0.f, s2 = 0.f, s3 = 0.f, s4 = 0.f, s5 = 0.f, s6 = 0.f, s7 = 0.f;
    float q0 = 0.f, q1 = 0.f, q2 = 0.f, q3 = 0.f, q4 = 0.f, q5 = 0.f, q6 = 0.f, q7 = 0.f;
    for (int row = blockIdx.x * 16 + grp; row < n; row += BN_BLOCKS * 16) {
        uint4 v = H4[(size_t)row * 16 + fg];
        float a;
        a = bf_lo(v.x); s0 += a; q0 += a * a;
        a = bf_hi(v.x); s1 += a; q1 += a * a;
        a = bf_lo(v.y); s2 += a; q2 += a * a;
        a = bf_hi(v.y); s3 += a; q3 += a * a;
        a = bf_lo(v.z); s4 += a; q4 += a * a;
        a = bf_hi(v.z); s5 += a; q5 += a * a;
        a = bf_lo(v.w); s6 += a; q6 += a * a;
        a = bf_hi(v.w); s7 += a; q7 += a * a;
    }
    __shared__ float lsum[16][136];
    __shared__ float lsq[16][136];
    int ch = fg * 8;
    lsum[grp][ch + 0] = s0; lsum[grp][ch + 1] = s1; lsum[grp][ch + 2] = s2; lsum[grp][ch + 3] = s3;
    lsum[grp][ch + 4] = s4; lsum[grp][ch + 5] = s5; lsum[grp][ch + 6] = s6; lsum[grp][ch + 7] = s7;
    lsq[grp][ch + 0] = q0; lsq[grp][ch + 1] = q1; lsq[grp][ch + 2] = q2; lsq[grp][ch + 3] = q3;
    lsq[grp][ch + 4] = q4; lsq[grp][ch + 5] = q5; lsq[grp][ch + 6] = q6; lsq[grp][ch + 7] = q7;
    __syncthreads();
    // partials slot layout (channel-major): [0:128)=sum[ch], [128:256)=sq[ch]
    if (tid < 128) {
        float s = 0.f;
#pragma unroll
        for (int g2 = 0; g2 < 16; ++g2) s += lsum[g2][tid];
        partials[(size_t)blockIdx.x * 256 + tid] = s;
    } else {
        int c2 = tid - 128;
        float q = 0.f;
#pragma unroll
        for (int g2 = 0; g2 < 16; ++g2) q += lsq[g2][c2];
        partials[(size_t)blockIdx.x * 256 + tid] = q;
    }
    __threadfence();
    __shared__ int lastFlag;
    if (tid == 0) lastFlag = (atomicAdd(ticket, 1) == BN_BLOCKS - 1);
    __syncthreads();
    if (!lastFlag) return;
    __threadfence();
    // last block: coalesced float4 reduce, 4 slots per iteration
    int g = tid >> 6;                  // slot group 0..3
    int j = (tid & 63) * 4;            // float4 position within a slot
    floatx4 a4 = {};
#pragma unroll 8
    for (int b = g; b < BN_BLOCKS; b += 4) {
        floatx4 v = *(const floatx4*)&partials[(size_t)b * 256 + j];
        a4 += v;
    }
    __shared__ floatx4 red[256];
    red[tid] = a4;
    __syncthreads();
    if (tid < 64) {
        floatx4 r = red[tid] + red[tid + 64] + red[tid + 128] + red[tid + 192];
#pragma unroll
        for (int k = 0; k < 4; ++k) {
            int p2 = 4 * tid + k;      // position in 256-vector
            if (p2 < 128) gsum[p2] = r[k];
            else          gsq[p2 - 128] = r[k];
        }
    }
}

// ---------------- pool (bn2 from raw stats + relu) + classify + log_softmax ----------------
__global__ __launch_bounds__(256) void pool_classify_kernel(
    const u32* __restrict__ H, const float* __restrict__ gsum, const float* __restrict__ gsq,
    const float* __restrict__ gamma, const float* __restrict__ beta, float invN,
    const int* __restrict__ gstart, const float* __restrict__ fcw,
    const float* __restrict__ fcb, float* __restrict__ out)
{
    int g = blockIdx.x;
    int tid = threadIdx.x;
    int c = tid & 63, q = tid >> 6;
    // bn2 scale/shift for features 2c, 2c+1 (redundant across q — cheap)
    float muA = gsum[2 * c] * invN, muB = gsum[2 * c + 1] * invN;
    float vA = gsq[2 * c] * invN - muA * muA, vB = gsq[2 * c + 1] * invN - muB * muB;
    float scA = gamma[2 * c] * rsqrtf(vA + BN_EPS), scB = gamma[2 * c + 1] * rsqrtf(vB + BN_EPS);
    float shA = beta[2 * c] - muA * scA, shB = beta[2 * c + 1] - muB * scB;

    int s = gstart[g], cnt = gstart[g + 1] - s;
    float aA = 0.f, aB = 0.f;
    for (int i = q; i < cnt; i += 4) {
        u32 v = H[(size_t)(s + i) * 64 + c];
        aA += fmaxf(bf_lo(v) * scA + shA, 0.f);
        aB += fmaxf(bf_hi(v) * scB + shB, 0.f);
    }
    __shared__ float sA[256], sB[256];
    __shared__ float prow[D];
    __shared__ float lg[C_CLASSES];
    sA[tid] = aA; sB[tid] = aB;
    __syncthreads();
    if (tid < 64) {
        float tA = sA[tid] + sA[tid + 64] + sA[tid + 128] + sA[tid + 192];
        float tB = sB[tid] + sB[tid + 64] + sB[tid + 128] + sB[tid + 192];
        float inv = 1.f / (float)(cnt > 1 ? cnt : 1);
        prow[2 * tid] = tA * inv;
        prow[2 * tid + 1] = tB * inv;
    }
    __syncthreads();
    if (tid < C_CLASSES) {
        float sum = fcb[tid];
        for (int d = 0; d < D; ++d) sum += prow[d] * fcw[d * C_CLASSES + tid];
        lg[tid] = sum;
    }
    __syncthreads();
    if (tid == 0) {
        float mx = -1e30f;
        for (int k = 0; k < C_CLASSES; ++k) mx = fmaxf(mx, lg[k]);
        float se = 0.f;
        for (int k = 0; k < C_CLASSES; ++k) se += expf(lg[k] - mx);
        float lse = mx + logf(se);
        for (int k = 0; k < C_CLASSES; ++k) out[(size_t)g * C_CLASSES + k] = lg[k] - lse;
    }
}

extern "C" void kernel_launch(void* const* d_in, const int* in_sizes, int n_in,
                              void* d_out, int out_size, void* d_ws, size_t ws_size,
                              hipStream_t stream) {
    const float* x   = (const float*)d_in[0];
    const int* ei    = (const int*)d_in[1];
    const int* batch = (const int*)d_in[2];
    const float* w1  = (const float*)d_in[3];
    const float* b1  = (const float*)d_in[4];
    const float* w2  = (const float*)d_in[5];
    const float* b2  = (const float*)d_in[6];
    const float* w3  = (const float*)d_in[7];
    const float* b3  = (const float*)d_in[8];
    const float* g1  = (const float*)d_in[9];
    const float* be1 = (const float*)d_in[10];
    const float* g2  = (const float*)d_in[11];
    const float* be2 = (const float*)d_in[12];
    const float* fcw = (const float*)d_in[13];
    const float* fcb = (const float*)d_in[14];

    const int N = in_sizes[0] / D;
    const int E = in_sizes[1] / 2;
    const int* src = ei;
    const int* dst = ei + E;
    const int nbuck = (N + 255) >> 8;
    const float invN = 1.f / (float)N;

    char* p = (char*)d_ws;
    auto alloc = [&](size_t bytes) -> void* {
        void* r = (void*)p;
        p += (bytes + 255) & ~(size_t)255;
        return r;
    };
    // memset span: bucketCnt(2048) + statsacc(2048) + degHist(2048) + bnTick(256)
    int*   bucketCnt    = (int*)alloc(NBUCK_MAX * 4);
    float* statsacc     = (float*)alloc(4 * D * 4);
    float* gsum1 = statsacc, *gsq1 = statsacc + D, *gsum2 = statsacc + 2 * D, *gsq2 = statsacc + 3 * D;
    int*   degHist      = (int*)alloc(2 * 16 * 16 * 4);   // 16 bins @ 64B stride + 16 cursors
    int*   degCursor    = degHist + 256;
    int*   bnTick       = (int*)alloc(256);               // bnTick[0], bnTick[16]
    float* dinv     = (float*)alloc((size_t)N * 4);
    int*   rowPtr   = (int*)alloc((size_t)(N + 1) * 4);
    int*   colIdx   = (int*)alloc((size_t)E * 4);
    u32*   pairs    = (u32*)alloc((size_t)E * 4);   // must follow colIdx (OOB-read slack)
    int*   bucketBase   = (int*)alloc((NBUCK_MAX + 1) * 4);
    int*   bucketCursor = (int*)alloc(NBUCK_MAX * 4);
    int*   gstart  = (int*)alloc((G_GRAPHS + 1) * 4);
    int*   perm    = (int*)alloc((size_t)N * 4);
    float* bnPart  = (float*)alloc((size_t)BN_BLOCKS * 256 * 4);   // 512KB partials
    u16*   wtAll   = (u16*)alloc((size_t)3 * D * D * 2);       // bf16 W^T x3
    u16*   tmp     = (u16*)alloc((size_t)(N + 1) * D * 2);     // bf16 gemm out + zero row N
    u16*   hbuf    = (u16*)alloc((size_t)N * D * 2);           // bf16 agg out

    hipMemsetAsync(bucketCnt, 0, NBUCK_MAX * 4 + 4 * D * 4 + 2 * 16 * 16 * 4 + 256, stream);

    // ---- graph structure (graph_bounds folded into bucket_hist: blocks >= 512) ----
    bucket_hist_kernel<<<HIST_BLOCKS + (N + 255) / 256, 256, 0, stream>>>(
        dst, bucketCnt, E, nbuck, batch, gstart, N);
    scan_buckets_kernel<<<1, 512, 0, stream>>>(bucketCnt, bucketBase, bucketCursor, rowPtr, nbuck, N, E);
    scatter_pairs_kernel<<<(E + EDGE_CHUNK - 1) / EDGE_CHUNK, 256, 0, stream>>>(src, dst, bucketCursor, pairs, E);
    bucket_sort_kernel<<<nbuck, 256, 0, stream>>>(pairs, bucketBase, colIdx, rowPtr, dinv, degHist, N);
    wconv_kernel<<<5, 256, 0, stream>>>((const float4*)w1, (const float4*)w2, (const float4*)w3,
                                        wtAll, (u32*)(tmp + (size_t)N * D), degHist, degCursor);
    perm_scatter_kernel<<<(N + 255) / 256, 256, 0, stream>>>(rowPtr, degCursor, perm, N);

    const int NT = (N + 63) / 64;            // gemm tiles
    const int GB = NT < GEMM_GRID ? NT : GEMM_GRID;
    const int AB = (N + 15) / 16;            // aggregate blocks: 16 rows/block
    const u32 ZOFF = (u32)N << 8;            // byte offset of zero row

    gemm_mfma_f32in_kernel<<<GB, 256, 0, stream>>>((const float4*)x, wtAll, dinv, tmp, N, NT);
    aggregate_kernel<<<AB, 256, 0, stream>>>((const uint4*)tmp, colIdx, rowPtr, dinv, b1, perm, (u32*)hbuf, N, ZOFF);
    gemm_mfma_bf16in_kernel<<<GB, 256, 0, stream>>>((const uint4*)hbuf, wtAll + D * D,
        nullptr, nullptr, nullptr, nullptr, 0.f, dinv, tmp, N, NT);
    aggregate_kernel<<<AB, 256, 0, stream>>>((const uint4*)tmp, colIdx, rowPtr, dinv, b2, perm, (u32*)hbuf, N, ZOFF);
    bn_stats_kernel<<<BN_BLOCKS, 256, 0, stream>>>((const uint4*)hbuf, N, bnPart, bnTick, gsum1, gsq1);
    gemm_mfma_bf16in_kernel<<<GB, 256, 0, stream>>>((const uint4*)hbuf, wtAll + 2 * D * D,
        gsum1, gsq1, g1, be1, invN, dinv, tmp, N, NT);
    aggregate_kernel<<<AB, 256, 0, stream>>>((const uint4*)tmp, colIdx, rowPtr, dinv, b3, perm, (u32*)hbuf, N, ZOFF);
    bn_stats_kernel<<<BN_BLOCKS, 256, 0, stream>>>((const uint4*)hbuf, N, bnPart, bnTick + 16, gsum2, gsq2);
    pool_classify_kernel<<<G_GRAPHS, 256, 0, stream>>>((const u32*)hbuf, gsum2, gsq2, g2, be2, invN,
        gstart, fcw, fcb, (float*)d_out);
}